// Round 6
// baseline (255.792 us; speedup 1.0000x reference)
//
#include <hip/hip_runtime.h>
#include <hip/hip_bf16.h>

#define B_ROWS 4096
#define D_DIM  512
#define N_ROWS 8192   // 2B
#define BMH 128       // block rows (half of a 256-row band)
#define BN  256       // block cols
#define BK  64
#define NBLK2 32                            // 256-row bands
#define NPAIR (NBLK2 * (NBLK2 + 1) / 2)     // 528 upper-tri band pairs
#define NBLOCKS (NPAIR * 2)                 // 1056 (each pair split into 2 row-halves)

typedef __bf16 bf16x8 __attribute__((ext_vector_type(8)));
typedef float  f32x4  __attribute__((ext_vector_type(4)));

// ---------------------------------------------------------------------------
// Kernel 1: per-pair prep. Block r computes norms, pos[r] (fp32 exact),
// normalized bf16 rows Z[r], Z[r+B]; zeroes row_sum and the completion ctr.
// ---------------------------------------------------------------------------
__global__ __launch_bounds__(256) void prep_kernel(
    const float* __restrict__ poly, const float* __restrict__ cemb,
    __bf16* __restrict__ Z, float* __restrict__ row_sum,
    float* __restrict__ pos, unsigned int* __restrict__ counter)
{
    const int r = blockIdx.x;
    const int t = threadIdx.x;
    const float* prow = poly + (size_t)r * D_DIM;
    const float* crow = cemb + (size_t)r * D_DIM;

    float p0 = prow[t], p1 = prow[t + 256];
    float c0 = crow[t], c1 = crow[t + 256];

    float ssp = p0 * p0 + p1 * p1;
    float ssc = c0 * c0 + c1 * c1;
    float dt  = p0 * c0 + p1 * c1;

    #pragma unroll
    for (int m = 1; m < 64; m <<= 1) {
        ssp += __shfl_xor(ssp, m);
        ssc += __shfl_xor(ssc, m);
        dt  += __shfl_xor(dt,  m);
    }
    __shared__ float red[3][4];
    const int wave = t >> 6;
    if ((t & 63) == 0) { red[0][wave] = ssp; red[1][wave] = ssc; red[2][wave] = dt; }
    __syncthreads();
    ssp = red[0][0] + red[0][1] + red[0][2] + red[0][3];
    ssc = red[1][0] + red[1][1] + red[1][2] + red[1][3];
    dt  = red[2][0] + red[2][1] + red[2][2] + red[2][3];

    const float sp = 1.0f / fmaxf(sqrtf(ssp), 1e-12f);
    const float sc = 1.0f / fmaxf(sqrtf(ssc), 1e-12f);

    __bf16* zp = Z + (size_t)r * D_DIM;
    __bf16* zc = Z + (size_t)(r + B_ROWS) * D_DIM;
    zp[t]       = (__bf16)(p0 * sp);
    zp[t + 256] = (__bf16)(p1 * sp);
    zc[t]       = (__bf16)(c0 * sc);
    zc[t + 256] = (__bf16)(c1 * sc);

    if (t == 0) {
        pos[r] = dt * sp * sc;
        row_sum[2 * r]     = 0.0f;
        row_sum[2 * r + 1] = 0.0f;
        if (r == 0) *counter = 0u;
    }
}

// ---------------------------------------------------------------------------
// Kernel 2: symmetric sim = Z Z^T. 528 upper-tri 256x256 band pairs, each
// split into two 128x256 blocks -> 1056 blocks, ~4.1/CU, sized for 2
// co-resident blocks/CU (8 waves, 48KB LDS) so one block's staging overlaps
// the other's MFMA. XOR chunk swizzle (0 bank conflicts). Strict gj>gi
// predicate excludes the diagonal exactly. Epilogue pre-reduces into LDS
// (384 global atomics/block instead of 2048). Last finished block (fence +
// agent-scope counter) computes the final loss -> no separate kernel.
// ---------------------------------------------------------------------------
__global__ __launch_bounds__(512, 4) void sim_kernel(
    const __bf16* __restrict__ Z, float* __restrict__ row_sum,
    const float* __restrict__ pos, float* __restrict__ out,
    unsigned int* __restrict__ counter)
{
    __shared__ __align__(16) __bf16 As[BMH * BK];   // 16 KB
    __shared__ __align__(16) __bf16 Bs[BN * BK];    // 32 KB
    __shared__ float rAcc[BMH];
    __shared__ float cAcc[BN];
    __shared__ unsigned int lastFlag;

    // decode blockIdx.x -> (pair, half); pair -> (bi, bj), bi <= bj < 32
    const int pairIdx = blockIdx.x >> 1;
    const int half    = blockIdx.x & 1;
    int bi = (int)((65.0f - sqrtf(4225.0f - 8.0f * (float)pairIdx)) * 0.5f);
    #define CFN(b) ((b) * (65 - (b)) / 2)
    while (CFN(bi + 1) <= pairIdx) ++bi;
    while (CFN(bi) > pairIdx) --bi;
    const int bj = bi + (pairIdx - CFN(bi));
    #undef CFN

    const int ibase = bi * 256 + half * BMH;   // 128-row slab
    const int jbase = bj * 256;                // 256-col slab
    const int tid   = threadIdx.x;             // 0..511

    const int srow = tid >> 3;                 // 0..63
    const int gchk = (tid & 7) ^ (srow & 7);   // swizzled source chunk (16B)

    const int wave = tid >> 6;                 // 0..7
    const int lane = tid & 63;
    const int wi = (wave >> 2) * 64;           // 0,64
    const int wj = (wave & 3) * 64;            // 0,64,128,192
    const int quad = lane >> 4;
    const int c    = lane & 15;

    f32x4 acc[4][4] = {};

    for (int k0 = 0; k0 < D_DIM; k0 += BK) {
        // A: 128x64 (2 shots of 64 rows); LDS offsets in ELEMENTS
        #pragma unroll
        for (int it = 0; it < 2; ++it) {
            const int row = it * 64 + srow;
            const __bf16* ga = Z + (size_t)(ibase + row) * D_DIM + k0 + gchk * 8;
            __builtin_amdgcn_global_load_lds(
                (const __attribute__((address_space(1))) void*)ga,
                (__attribute__((address_space(3))) void*)(As + it * 4096 + tid * 8),
                16, 0, 0);
        }
        // B: 256x64 (4 shots)
        #pragma unroll
        for (int it = 0; it < 4; ++it) {
            const int row = it * 64 + srow;
            const __bf16* gb = Z + (size_t)(jbase + row) * D_DIM + k0 + gchk * 8;
            __builtin_amdgcn_global_load_lds(
                (const __attribute__((address_space(1))) void*)gb,
                (__attribute__((address_space(3))) void*)(Bs + it * 4096 + tid * 8),
                16, 0, 0);
        }
        __syncthreads();

        #pragma unroll
        for (int kk = 0; kk < BK; kk += 32) {
            const int sw = ((kk >> 3) + quad) ^ (c & 7);  // reader swizzle
            bf16x8 a[4], b[4];
            #pragma unroll
            for (int ti = 0; ti < 4; ++ti)
                a[ti] = *(const bf16x8*)&As[(wi + ti * 16 + c) * BK + sw * 8];
            #pragma unroll
            for (int tj = 0; tj < 4; ++tj)
                b[tj] = *(const bf16x8*)&Bs[(wj + tj * 16 + c) * BK + sw * 8];
            #pragma unroll
            for (int ti = 0; ti < 4; ++ti)
                #pragma unroll
                for (int tj = 0; tj < 4; ++tj)
                    acc[ti][tj] = __builtin_amdgcn_mfma_f32_16x16x32_bf16(
                        a[ti], b[tj], acc[ti][tj], 0, 0, 0);
        }
        __syncthreads();
    }

    // ---- Epilogue: strict-upper exp(sim/T), pre-reduced in LDS ----
    if (tid < BMH) rAcc[tid] = 0.0f;
    if (tid < BN)  cAcc[tid] = 0.0f;
    __syncthreads();

    const float K2 = 2.885390081777927f;  // 2*log2(e) = 1/(T*ln2)
    float col[4] = {0.0f, 0.0f, 0.0f, 0.0f};
    #pragma unroll
    for (int ti = 0; ti < 4; ++ti) {
        const int li = wi + ti * 16 + quad * 4;   // local row base
        #pragma unroll
        for (int r = 0; r < 4; ++r) {
            const int gi = ibase + li + r;
            float v = 0.0f;
            #pragma unroll
            for (int tj = 0; tj < 4; ++tj) {
                const int gj = jbase + wj + tj * 16 + c;
                const float e = (gj > gi) ? exp2f(K2 * acc[ti][tj][r]) : 0.0f;
                v += e;
                col[tj] += e;
            }
            v += __shfl_xor(v, 1);
            v += __shfl_xor(v, 2);
            v += __shfl_xor(v, 4);
            v += __shfl_xor(v, 8);
            if (c == 0)
                atomicAdd(&rAcc[li + r], v);
        }
    }
    #pragma unroll
    for (int tj = 0; tj < 4; ++tj) {
        float w = col[tj];
        w += __shfl_xor(w, 16);
        w += __shfl_xor(w, 32);
        if (quad == 0)
            atomicAdd(&cAcc[wj + tj * 16 + c], w);
    }
    __syncthreads();

    if (tid < BMH)
        atomicAdd(&row_sum[ibase + tid], rAcc[tid]);
    else if (tid < BMH + BN)
        atomicAdd(&row_sum[jbase + tid - BMH], cAcc[tid - BMH]);

    // ---- Completion count; last block computes the loss ----
    __threadfence();          // publish this block's row_sum adds (agent scope)
    __syncthreads();
    if (tid == 0) {
        unsigned int old = __hip_atomic_fetch_add(
            counter, 1u, __ATOMIC_ACQ_REL, __HIP_MEMORY_SCOPE_AGENT);
        lastFlag = (old == NBLOCKS - 1) ? 1u : 0u;
    }
    __syncthreads();
    if (lastFlag) {
        float accL = 0.0f, accP = 0.0f;
        for (int i = tid; i < N_ROWS; i += 512) {
            const float rs = __hip_atomic_load(
                &row_sum[i], __ATOMIC_RELAXED, __HIP_MEMORY_SCOPE_AGENT);
            accL += __logf(rs);
        }
        for (int r = tid; r < B_ROWS; r += 512)
            accP += pos[r];
        #pragma unroll
        for (int m = 1; m < 64; m <<= 1) {
            accL += __shfl_xor(accL, m);
            accP += __shfl_xor(accP, m);
        }
        if (lane == 0) { rAcc[wave] = accL; cAcc[wave] = accP; }
        __syncthreads();
        if (tid == 0) {
            float L = 0.0f, P = 0.0f;
            #pragma unroll
            for (int w = 0; w < 8; ++w) { L += rAcc[w]; P += cAcc[w]; }
            out[0] = (L - 4.0f * P) / (float)N_ROWS;
        }
    }
}

extern "C" void kernel_launch(void* const* d_in, const int* in_sizes, int n_in,
                              void* d_out, int out_size, void* d_ws, size_t ws_size,
                              hipStream_t stream) {
    const float* poly = (const float*)d_in[0];
    const float* cemb = (const float*)d_in[1];

    __bf16*       Z       = (__bf16*)d_ws;
    float*        row_sum = (float*)((char*)d_ws + (size_t)N_ROWS * D_DIM * sizeof(__bf16));
    float*        pos     = row_sum + N_ROWS;
    unsigned int* counter = (unsigned int*)(pos + B_ROWS);
    float*        out     = (float*)d_out;

    prep_kernel<<<B_ROWS, 256, 0, stream>>>(poly, cemb, Z, row_sum, pos, counter);
    sim_kernel<<<NBLOCKS, 512, 0, stream>>>(Z, row_sum, pos, out, counter);
}

// Round 7
// 155.698 us; speedup vs baseline: 1.6429x; 1.6429x over previous
//
#include <hip/hip_runtime.h>
#include <hip/hip_bf16.h>

#define B_ROWS 4096
#define D_DIM  512
#define N_ROWS 8192   // 2B
#define BM 128
#define BN 128
#define BK 64
#define NBLK (N_ROWS / BM)             // 64 row-blocks
#define NPAIR (NBLK * (NBLK + 1) / 2)  // 2080 upper-tri block pairs

typedef __bf16 bf16x8 __attribute__((ext_vector_type(8)));
typedef float  f32x4  __attribute__((ext_vector_type(4)));

// ---------------------------------------------------------------------------
// Kernel 1: per-pair prep. Block r computes norms, pos[r] (fp32 exact),
// normalized bf16 rows Z[r], Z[r+B]; zeroes row_sum and the completion ctr.
// ---------------------------------------------------------------------------
__global__ __launch_bounds__(256) void prep_kernel(
    const float* __restrict__ poly, const float* __restrict__ cemb,
    __bf16* __restrict__ Z, float* __restrict__ row_sum,
    float* __restrict__ pos, unsigned int* __restrict__ counter)
{
    const int r = blockIdx.x;
    const int t = threadIdx.x;
    const float* prow = poly + (size_t)r * D_DIM;
    const float* crow = cemb + (size_t)r * D_DIM;

    float p0 = prow[t], p1 = prow[t + 256];
    float c0 = crow[t], c1 = crow[t + 256];

    float ssp = p0 * p0 + p1 * p1;
    float ssc = c0 * c0 + c1 * c1;
    float dt  = p0 * c0 + p1 * c1;

    #pragma unroll
    for (int m = 1; m < 64; m <<= 1) {
        ssp += __shfl_xor(ssp, m);
        ssc += __shfl_xor(ssc, m);
        dt  += __shfl_xor(dt,  m);
    }
    __shared__ float red[3][4];
    const int wave = t >> 6;
    if ((t & 63) == 0) { red[0][wave] = ssp; red[1][wave] = ssc; red[2][wave] = dt; }
    __syncthreads();
    ssp = red[0][0] + red[0][1] + red[0][2] + red[0][3];
    ssc = red[1][0] + red[1][1] + red[1][2] + red[1][3];
    dt  = red[2][0] + red[2][1] + red[2][2] + red[2][3];

    const float sp = 1.0f / fmaxf(sqrtf(ssp), 1e-12f);
    const float sc = 1.0f / fmaxf(sqrtf(ssc), 1e-12f);

    __bf16* zp = Z + (size_t)r * D_DIM;
    __bf16* zc = Z + (size_t)(r + B_ROWS) * D_DIM;
    zp[t]       = (__bf16)(p0 * sp);
    zp[t + 256] = (__bf16)(p1 * sp);
    zc[t]       = (__bf16)(c0 * sc);
    zc[t + 256] = (__bf16)(c1 * sc);

    if (t == 0) {
        pos[r] = dt * sp * sc;
        row_sum[2 * r]     = 0.0f;
        row_sum[2 * r + 1] = 0.0f;
        if (r == 0) *counter = 0u;
    }
}

// ---------------------------------------------------------------------------
// Kernel 2: symmetric sim = Z Z^T, 128x128 tiles over upper-tri block pairs
// (round-2 core: 256 thr, 4 waves 2x2, XOR-swizzled global_load_lds staging,
// 0 bank conflicts). Strict gj>gi predicate excludes the diagonal exactly;
// each strictly-upper element feeds row_sum[gi] and row_sum[gj]. Epilogue
// pre-reduces in LDS (256 global atomics/block). Diag blocks reuse As as Bs.
// Fused finalize: relaxed agent-scope completion counter — NO __threadfence
// (the round-6 2.3x regression was the per-block L2 writeback it implied);
// the pre-increment __syncthreads already drains this block's atomics
// (barrier implies vmcnt(0)), and device-scope atomicAdds commit at the
// coherence point. Last block reads row_sum via relaxed agent atomic loads.
// ---------------------------------------------------------------------------
__global__ __launch_bounds__(256) void sim_kernel(
    const __bf16* __restrict__ Z, float* __restrict__ row_sum,
    const float* __restrict__ pos, float* __restrict__ out,
    unsigned int* __restrict__ counter)
{
    __shared__ __align__(16) __bf16 As[BM * BK];   // 16 KB
    __shared__ __align__(16) __bf16 Bs[BN * BK];   // 16 KB
    __shared__ float rAcc[BM];
    __shared__ float cAcc[BN];
    __shared__ unsigned int lastFlag;

    // decode blockIdx.x -> (bi, bj), bi <= bj < 64; C(b) = b*(129-b)/2
    const int t0 = blockIdx.x;
    int bi = (int)((129.0f - sqrtf(16641.0f - 8.0f * (float)t0)) * 0.5f);
    #define CFN(b) ((b) * (129 - (b)) / 2)
    while (CFN(bi + 1) <= t0) ++bi;
    while (CFN(bi) > t0) --bi;
    const int bj = bi + (t0 - CFN(bi));
    #undef CFN
    const bool diag = (bi == bj);

    const int ibase = bi * BM;
    const int jbase = bj * BN;
    const int tid   = threadIdx.x;

    const int srow = tid >> 3;                 // staging row within 32-row group
    const int gchk = (tid & 7) ^ (srow & 7);   // swizzled source chunk (16B units)

    const int wave = tid >> 6;
    const int lane = tid & 63;
    const int wi = (wave >> 1) * 64;
    const int wj = (wave & 1) * 64;
    const int quad = lane >> 4;
    const int c    = lane & 15;

    f32x4 acc[4][4] = {};

    for (int k0 = 0; k0 < D_DIM; k0 += BK) {
        #pragma unroll
        for (int it = 0; it < 4; ++it) {
            const int row = it * 32 + srow;
            const __bf16* ga = Z + (size_t)(ibase + row) * D_DIM + k0 + gchk * 8;
            __builtin_amdgcn_global_load_lds(
                (const __attribute__((address_space(1))) void*)ga,
                (__attribute__((address_space(3))) void*)(As + it * 2048 + tid * 8),
                16, 0, 0);
        }
        if (!diag) {
            #pragma unroll
            for (int it = 0; it < 4; ++it) {
                const int row = it * 32 + srow;
                const __bf16* gb = Z + (size_t)(jbase + row) * D_DIM + k0 + gchk * 8;
                __builtin_amdgcn_global_load_lds(
                    (const __attribute__((address_space(1))) void*)gb,
                    (__attribute__((address_space(3))) void*)(Bs + it * 2048 + tid * 8),
                    16, 0, 0);
            }
        }
        __syncthreads();

        const __bf16* bsrc = diag ? As : Bs;
        #pragma unroll
        for (int kk = 0; kk < BK; kk += 32) {
            const int sw = ((kk >> 3) + quad) ^ (c & 7);  // reader swizzle
            bf16x8 a[4], b[4];
            #pragma unroll
            for (int ti = 0; ti < 4; ++ti)
                a[ti] = *(const bf16x8*)&As[(wi + ti * 16 + c) * BK + sw * 8];
            #pragma unroll
            for (int tj = 0; tj < 4; ++tj)
                b[tj] = *(const bf16x8*)&bsrc[(wj + tj * 16 + c) * BK + sw * 8];
            #pragma unroll
            for (int ti = 0; ti < 4; ++ti)
                #pragma unroll
                for (int tj = 0; tj < 4; ++tj)
                    acc[ti][tj] = __builtin_amdgcn_mfma_f32_16x16x32_bf16(
                        a[ti], b[tj], acc[ti][tj], 0, 0, 0);
        }
        __syncthreads();
    }

    // ---- Epilogue: strict-upper exp(sim/T), pre-reduced in LDS ----
    if (tid < BM) rAcc[tid] = 0.0f;
    rAcc[tid < BM ? tid : 0] = 0.0f;  // (kept simple below)
    cAcc[tid & (BN - 1)] = 0.0f;      // 256 threads cover 128 twice; harmless
    __syncthreads();

    const float K2 = 2.885390081777927f;  // 2*log2(e) = 1/(T*ln2)
    float col[4] = {0.0f, 0.0f, 0.0f, 0.0f};
    #pragma unroll
    for (int ti = 0; ti < 4; ++ti) {
        const int li = wi + ti * 16 + quad * 4;
        #pragma unroll
        for (int r = 0; r < 4; ++r) {
            const int gi = ibase + li + r;
            float v = 0.0f;
            #pragma unroll
            for (int tj = 0; tj < 4; ++tj) {
                const int gj = jbase + wj + tj * 16 + c;
                const float e = (gj > gi) ? exp2f(K2 * acc[ti][tj][r]) : 0.0f;
                v += e;
                col[tj] += e;
            }
            v += __shfl_xor(v, 1);
            v += __shfl_xor(v, 2);
            v += __shfl_xor(v, 4);
            v += __shfl_xor(v, 8);
            if (c == 0)
                atomicAdd(&rAcc[li + r], v);
        }
    }
    #pragma unroll
    for (int tj = 0; tj < 4; ++tj) {
        float w = col[tj];
        w += __shfl_xor(w, 16);
        w += __shfl_xor(w, 32);
        if (quad == 0)
            atomicAdd(&cAcc[wj + tj * 16 + c], w);
    }
    __syncthreads();

    if (tid < BM)
        atomicAdd(&row_sum[ibase + tid], rAcc[tid]);
    else
        atomicAdd(&row_sum[jbase + tid - BM], cAcc[tid - BM]);

    // ---- Completion count; last block computes the loss (fence-free) ----
    __syncthreads();   // barrier implies vmcnt(0): this block's atomics done
    if (tid == 0) {
        unsigned int old = __hip_atomic_fetch_add(
            counter, 1u, __ATOMIC_RELAXED, __HIP_MEMORY_SCOPE_AGENT);
        lastFlag = (old == NPAIR - 1) ? 1u : 0u;
    }
    __syncthreads();
    if (lastFlag) {
        float accL = 0.0f, accP = 0.0f;
        for (int i = tid; i < N_ROWS; i += 256) {
            const float rs = __hip_atomic_load(
                &row_sum[i], __ATOMIC_RELAXED, __HIP_MEMORY_SCOPE_AGENT);
            accL += __logf(rs);
        }
        for (int r = tid; r < B_ROWS; r += 256)
            accP += pos[r];
        #pragma unroll
        for (int m = 1; m < 64; m <<= 1) {
            accL += __shfl_xor(accL, m);
            accP += __shfl_xor(accP, m);
        }
        if (lane == 0) { rAcc[wave] = accL; cAcc[wave] = accP; }
        __syncthreads();
        if (tid == 0) {
            float L = 0.0f, P = 0.0f;
            #pragma unroll
            for (int w = 0; w < 4; ++w) { L += rAcc[w]; P += cAcc[w]; }
            out[0] = (L - 4.0f * P) / (float)N_ROWS;
        }
    }
}

extern "C" void kernel_launch(void* const* d_in, const int* in_sizes, int n_in,
                              void* d_out, int out_size, void* d_ws, size_t ws_size,
                              hipStream_t stream) {
    const float* poly = (const float*)d_in[0];
    const float* cemb = (const float*)d_in[1];

    __bf16*       Z       = (__bf16*)d_ws;
    float*        row_sum = (float*)((char*)d_ws + (size_t)N_ROWS * D_DIM * sizeof(__bf16));
    float*        pos     = row_sum + N_ROWS;
    unsigned int* counter = (unsigned int*)(pos + B_ROWS);
    float*        out     = (float*)d_out;

    prep_kernel<<<B_ROWS, 256, 0, stream>>>(poly, cemb, Z, row_sum, pos, counter);
    sim_kernel<<<NPAIR, 256, 0, stream>>>(Z, row_sum, pos, out, counter);
}

// Round 8
// 131.569 us; speedup vs baseline: 1.9442x; 1.1834x over previous
//
#include <hip/hip_runtime.h>
#include <hip/hip_bf16.h>

#define B_ROWS 4096
#define D_DIM  512
#define N_ROWS 8192   // 2B
#define BM 128
#define BN 128
#define BKB 128       // K-tile in BYTES (= fp8 elements); row stride 128B, 8x16B granules
#define NBLK (N_ROWS / BM)             // 64 row-blocks
#define NPAIR (NBLK * (NBLK + 1) / 2)  // 2080 upper-tri block pairs

typedef float f32x4 __attribute__((ext_vector_type(4)));

// ---------------------------------------------------------------------------
// Kernel 1: per-pair prep. Block r computes norms, pos[r] (fp32 exact),
// fp8-e4m3 normalized rows Z[r], Z[r+B]; zeroes row_sum and completion ctr.
// Thread t handles elements 2t, 2t+1 (adjacent, for packed fp8 conversion).
// ---------------------------------------------------------------------------
__global__ __launch_bounds__(256) void prep_kernel(
    const float* __restrict__ poly, const float* __restrict__ cemb,
    unsigned char* __restrict__ Z, float* __restrict__ row_sum,
    float* __restrict__ pos, unsigned int* __restrict__ counter)
{
    const int r = blockIdx.x;
    const int t = threadIdx.x;
    const float* prow = poly + (size_t)r * D_DIM;
    const float* crow = cemb + (size_t)r * D_DIM;

    const float2 pv = *(const float2*)(prow + 2 * t);
    const float2 cv = *(const float2*)(crow + 2 * t);

    float ssp = pv.x * pv.x + pv.y * pv.y;
    float ssc = cv.x * cv.x + cv.y * cv.y;
    float dt  = pv.x * cv.x + pv.y * cv.y;

    #pragma unroll
    for (int m = 1; m < 64; m <<= 1) {
        ssp += __shfl_xor(ssp, m);
        ssc += __shfl_xor(ssc, m);
        dt  += __shfl_xor(dt,  m);
    }
    __shared__ float red[3][4];
    const int wave = t >> 6;
    if ((t & 63) == 0) { red[0][wave] = ssp; red[1][wave] = ssc; red[2][wave] = dt; }
    __syncthreads();
    ssp = red[0][0] + red[0][1] + red[0][2] + red[0][3];
    ssc = red[1][0] + red[1][1] + red[1][2] + red[1][3];
    dt  = red[2][0] + red[2][1] + red[2][2] + red[2][3];

    const float sp = 1.0f / fmaxf(sqrtf(ssp), 1e-12f);
    const float sc = 1.0f / fmaxf(sqrtf(ssc), 1e-12f);

    unsigned char* zp = Z + (size_t)r * D_DIM;
    unsigned char* zc = Z + (size_t)(r + B_ROWS) * D_DIM;
    const int pk = __builtin_amdgcn_cvt_pk_fp8_f32(pv.x * sp, pv.y * sp, 0, false);
    const int ck = __builtin_amdgcn_cvt_pk_fp8_f32(cv.x * sc, cv.y * sc, 0, false);
    *(unsigned short*)(zp + 2 * t) = (unsigned short)(pk & 0xffff);
    *(unsigned short*)(zc + 2 * t) = (unsigned short)(ck & 0xffff);

    if (t == 0) {
        pos[r] = dt * sp * sc;
        row_sum[2 * r]     = 0.0f;
        row_sum[2 * r + 1] = 0.0f;
        if (r == 0) *counter = 0u;
    }
}

// ---------------------------------------------------------------------------
// Kernel 2: symmetric sim = Z Z^T in fp8 (mfma_f32_16x16x32_fp8_fp8; same
// MFMA rate as bf16, but Z = 4.2 MB ~ fits per-XCD L2 -> the ~95 MB / ~1 TB/s
// L2-miss fetch stream that bound rounds 2/5/7 collapses). 128x128 tiles over
// upper-tri pairs; BK=128 bytes (4 k0 iters, half the barriers). XOR granule
// swizzle as before (row stride still 128 B). Fragments: 8 B/lane (long),
// ds_read_b64, k = quad*8..+8. Strict gj>gi predicate; LDS-reduced epilogue;
// fence-free fused finalize (round-6 lesson: NO __threadfence).
// ---------------------------------------------------------------------------
__global__ __launch_bounds__(256) void sim_kernel(
    const unsigned char* __restrict__ Z, float* __restrict__ row_sum,
    const float* __restrict__ pos, float* __restrict__ out,
    unsigned int* __restrict__ counter)
{
    __shared__ __align__(16) unsigned char As[BM * BKB];   // 16 KB
    __shared__ __align__(16) unsigned char Bs[BN * BKB];   // 16 KB
    __shared__ float rAcc[BM];
    __shared__ float cAcc[BN];
    __shared__ unsigned int lastFlag;

    // decode blockIdx.x -> (bi, bj), bi <= bj < 64; C(b) = b*(129-b)/2
    const int t0 = blockIdx.x;
    int bi = (int)((129.0f - sqrtf(16641.0f - 8.0f * (float)t0)) * 0.5f);
    #define CFN(b) ((b) * (129 - (b)) / 2)
    while (CFN(bi + 1) <= t0) ++bi;
    while (CFN(bi) > t0) --bi;
    const int bj = bi + (t0 - CFN(bi));
    #undef CFN
    const bool diag = (bi == bj);

    const int ibase = bi * BM;
    const int jbase = bj * BN;
    const int tid   = threadIdx.x;

    const int srow = tid >> 3;                 // staging row within 32-row group
    const int gchk = (tid & 7) ^ (srow & 7);   // swizzled source granule (16B)

    const int wave = tid >> 6;
    const int lane = tid & 63;
    const int wi = (wave >> 1) * 64;
    const int wj = (wave & 1) * 64;
    const int quad = lane >> 4;
    const int c    = lane & 15;

    f32x4 acc[4][4] = {};

    for (int k0 = 0; k0 < D_DIM; k0 += BKB) {   // 4 iterations (bytes==elems)
        #pragma unroll
        for (int it = 0; it < 4; ++it) {
            const int row = it * 32 + srow;
            const unsigned char* ga = Z + (size_t)(ibase + row) * D_DIM + k0 + gchk * 16;
            __builtin_amdgcn_global_load_lds(
                (const __attribute__((address_space(1))) void*)ga,
                (__attribute__((address_space(3))) void*)(As + it * 4096 + tid * 16),
                16, 0, 0);
        }
        if (!diag) {
            #pragma unroll
            for (int it = 0; it < 4; ++it) {
                const int row = it * 32 + srow;
                const unsigned char* gb = Z + (size_t)(jbase + row) * D_DIM + k0 + gchk * 16;
                __builtin_amdgcn_global_load_lds(
                    (const __attribute__((address_space(1))) void*)gb,
                    (__attribute__((address_space(3))) void*)(Bs + it * 4096 + tid * 16),
                    16, 0, 0);
            }
        }
        __syncthreads();

        const unsigned char* bsrc = diag ? As : Bs;
        #pragma unroll
        for (int kk = 0; kk < BKB; kk += 32) {   // 4 kk-iters; 32 fp8 elems each
            // lane reads elems kk + quad*8 .. +8 : granule (kk>>4)+(quad>>1),
            // sub-offset (quad&1)*8, swizzled by c&7 (row & 7 == c & 7).
            const int sw  = ((kk >> 4) + (quad >> 1)) ^ (c & 7);
            const int sub = (quad & 1) * 8;
            long a[4], b[4];
            #pragma unroll
            for (int ti = 0; ti < 4; ++ti)
                a[ti] = *(const long*)&As[(wi + ti * 16 + c) * BKB + sw * 16 + sub];
            #pragma unroll
            for (int tj = 0; tj < 4; ++tj)
                b[tj] = *(const long*)&bsrc[(wj + tj * 16 + c) * BKB + sw * 16 + sub];
            #pragma unroll
            for (int ti = 0; ti < 4; ++ti)
                #pragma unroll
                for (int tj = 0; tj < 4; ++tj)
                    acc[ti][tj] = __builtin_amdgcn_mfma_f32_16x16x32_fp8_fp8(
                        a[ti], b[tj], acc[ti][tj], 0, 0, 0);
        }
        __syncthreads();
    }

    // ---- Epilogue: strict-upper exp(sim/T), pre-reduced in LDS ----
    if (tid < BM) { rAcc[tid] = 0.0f; cAcc[tid] = 0.0f; }
    __syncthreads();

    const float K2 = 2.885390081777927f;  // 2*log2(e) = 1/(T*ln2)
    float col[4] = {0.0f, 0.0f, 0.0f, 0.0f};
    #pragma unroll
    for (int ti = 0; ti < 4; ++ti) {
        const int li = wi + ti * 16 + quad * 4;
        #pragma unroll
        for (int r = 0; r < 4; ++r) {
            const int gi = ibase + li + r;
            float v = 0.0f;
            #pragma unroll
            for (int tj = 0; tj < 4; ++tj) {
                const int gj = jbase + wj + tj * 16 + c;
                const float e = (gj > gi) ? exp2f(K2 * acc[ti][tj][r]) : 0.0f;
                v += e;
                col[tj] += e;
            }
            v += __shfl_xor(v, 1);
            v += __shfl_xor(v, 2);
            v += __shfl_xor(v, 4);
            v += __shfl_xor(v, 8);
            if (c == 0)
                atomicAdd(&rAcc[li + r], v);
        }
    }
    #pragma unroll
    for (int tj = 0; tj < 4; ++tj) {
        float w = col[tj];
        w += __shfl_xor(w, 16);
        w += __shfl_xor(w, 32);
        if (quad == 0)
            atomicAdd(&cAcc[wj + tj * 16 + c], w);
    }
    __syncthreads();

    if (tid < BM)
        atomicAdd(&row_sum[ibase + tid], rAcc[tid]);
    else
        atomicAdd(&row_sum[jbase + tid - BM], cAcc[tid - BM]);

    // ---- Completion count; last block computes the loss (fence-free) ----
    __syncthreads();   // barrier implies vmcnt(0): this block's atomics issued
    if (tid == 0) {
        unsigned int old = __hip_atomic_fetch_add(
            counter, 1u, __ATOMIC_RELAXED, __HIP_MEMORY_SCOPE_AGENT);
        lastFlag = (old == NPAIR - 1) ? 1u : 0u;
    }
    __syncthreads();
    if (lastFlag) {
        float accL = 0.0f, accP = 0.0f;
        for (int i = tid; i < N_ROWS; i += 256) {
            const float rs = __hip_atomic_load(
                &row_sum[i], __ATOMIC_RELAXED, __HIP_MEMORY_SCOPE_AGENT);
            accL += __logf(rs);
        }
        for (int r = tid; r < B_ROWS; r += 256)
            accP += pos[r];
        #pragma unroll
        for (int m = 1; m < 64; m <<= 1) {
            accL += __shfl_xor(accL, m);
            accP += __shfl_xor(accP, m);
        }
        if (lane == 0) { rAcc[wave] = accL; cAcc[wave] = accP; }
        __syncthreads();
        if (tid == 0) {
            float L = 0.0f, P = 0.0f;
            #pragma unroll
            for (int w = 0; w < 4; ++w) { L += rAcc[w]; P += cAcc[w]; }
            out[0] = (L - 4.0f * P) / (float)N_ROWS;
        }
    }
}

extern "C" void kernel_launch(void* const* d_in, const int* in_sizes, int n_in,
                              void* d_out, int out_size, void* d_ws, size_t ws_size,
                              hipStream_t stream) {
    const float* poly = (const float*)d_in[0];
    const float* cemb = (const float*)d_in[1];

    unsigned char* Z       = (unsigned char*)d_ws;
    float*         row_sum = (float*)((char*)d_ws + (size_t)N_ROWS * D_DIM);
    float*         pos     = row_sum + N_ROWS;
    unsigned int*  counter = (unsigned int*)(pos + B_ROWS);
    float*         out     = (float*)d_out;

    prep_kernel<<<B_ROWS, 256, 0, stream>>>(poly, cemb, Z, row_sum, pos, counter);
    sim_kernel<<<NPAIR, 256, 0, stream>>>(Z, row_sum, pos, out, counter);
}